// Round 5
// baseline (441.716 us; speedup 1.0000x reference)
//
#include <hip/hip_runtime.h>
#include <hip/hip_bf16.h>

// SDNN: xw1 = x@w1[:, :1024]+b1 ; h[:,j]=relu(xw1[:,j]+h@w2[:,j]) j<1024 ;
//       out = h@w3[:1024]+x@w4+b2.
// R4->R5: GEMM-side restructure (recurrence frozen as control):
//   - gemm1 (x@w1') and x@w4' share A -> merged into ONE GEMM x@[w1'|w4']
//     (N=2048, grid 1024 WGs = 3-4 WG/CU vs 2; A staged once).
//   - gemm_out = hid@w3 (K=1024) + epilogue add of precomputed xw4 (bf16).
//   - hid aliases x_bf (dead after merged GEMM) -> workspace unchanged.

typedef __bf16 bf16x8 __attribute__((ext_vector_type(8)));
typedef float f32x4 __attribute__((ext_vector_type(4)));
typedef int i32x4 __attribute__((ext_vector_type(4)));

__device__ __forceinline__ void gload_lds16(const void* gsrc, void* ldst) {
#if __has_builtin(__builtin_amdgcn_global_load_lds)
  void* g = const_cast<void*>(gsrc);
  __builtin_amdgcn_global_load_lds((__attribute__((address_space(1))) void*)g,
                                   (__attribute__((address_space(3))) void*)ldst,
                                   16, 0, 0);
#else
  *(i32x4*)ldst = *(const i32x4*)gsrc;
#endif
}

// ---------- converts ----------
__global__ __launch_bounds__(256) void cvt_bf16x8(const float* __restrict__ src,
                                                  __hip_bfloat16* __restrict__ dst,
                                                  long n) {
  long i = ((long)blockIdx.x * blockDim.x + threadIdx.x) * 8;
  if (i >= n) return;
  f32x4 a = *(const f32x4*)(src + i);
  f32x4 b = *(const f32x4*)(src + i + 4);
  union { __hip_bfloat16 h[8]; i32x4 v; } u;
#pragma unroll
  for (int j = 0; j < 4; ++j) {
    u.h[j]     = __float2bfloat16(a[j]);
    u.h[4 + j] = __float2bfloat16(b[j]);
  }
  *(i32x4*)(dst + i) = u.v;
}

// dst[j][k] = (j < Juse) ? bf16(src[k][j]) : 0 ; dst is [.][Kuse]
__global__ __launch_bounds__(256) void transpose_cvt(const float* __restrict__ src,
                                                     __hip_bfloat16* __restrict__ dst,
                                                     int srcStride, int Kuse, int Juse) {
  __shared__ float tile[32][33];
  const int k0 = blockIdx.x * 32, j0 = blockIdx.y * 32;
  const int tx = threadIdx.x, ty = threadIdx.y;  // 32 x 8
#pragma unroll
  for (int i = 0; i < 4; ++i) {
    const int k = k0 + ty + i * 8, j = j0 + tx;
    tile[ty + i * 8][tx] = (j < Juse) ? src[(size_t)k * srcStride + j] : 0.f;
  }
  __syncthreads();
#pragma unroll
  for (int i = 0; i < 4; ++i) {
    const int j = j0 + ty + i * 8, k = k0 + tx;
    dst[(size_t)j * Kuse + k] = __float2bfloat16(tile[tx][ty + i * 8]);
  }
}

// ---------- bf16 MFMA GEMM (m97 structure), templated epilogue ----------
// A: [M][K] bf16 ; Bt: [N][K] bf16 ; K = row stride of both.
// EPI=0 (merged x@[w1|w4]): col<1024 -> C1(f32,[.][1024]) = acc+bias[col]
//                           col>=1024 -> C2(bf16,[.][1024]) = bf16(acc)
// EPI=1 (out): col<1000 -> C1(f32,[.][1000]) = acc + f32(ADD[row*1024+col]) + bias[col]
template <int EPI>
__global__ __launch_bounds__(256) void gemm_nt(
    const __hip_bfloat16* __restrict__ A, const __hip_bfloat16* __restrict__ Bt, int K,
    const float* __restrict__ bias, float* __restrict__ C1,
    __hip_bfloat16* __restrict__ C2, const __hip_bfloat16* __restrict__ ADD) {
  __shared__ __align__(16) __hip_bfloat16 As[128 * 64];
  __shared__ __align__(16) __hip_bfloat16 Bs[128 * 64];
  const int tid = threadIdx.x;
  const int l = tid & 63;
  const int w = tid >> 6;
  const int wr = w >> 1, wc = w & 1;
  const int bm = blockIdx.x * 128;
  const int bn = blockIdx.y * 128;

  f32x4 acc[4][4] = {};

  for (int kt = 0; kt < K; kt += 64) {
    __syncthreads();
    const int srow = tid >> 3;
    const int sk = (tid & 7) * 8;
#pragma unroll
    for (int i = 0; i < 4; ++i) {
      gload_lds16(A  + (size_t)(bm + i * 32 + srow) * K + kt + sk,
                  &As[(i * 32 + srow) * 64 + sk]);
      gload_lds16(Bt + (size_t)(bn + i * 32 + srow) * K + kt + sk,
                  &Bs[(i * 32 + srow) * 64 + sk]);
    }
    __syncthreads();
#pragma unroll
    for (int kk = 0; kk < 64; kk += 32) {
      const int ko = kk + (l >> 4) * 8;
      bf16x8 aq[4], bq[4];
#pragma unroll
      for (int m = 0; m < 4; ++m)
        aq[m] = *(const bf16x8*)&As[(wr * 64 + m * 16 + (l & 15)) * 64 + ko];
#pragma unroll
      for (int n = 0; n < 4; ++n)
        bq[n] = *(const bf16x8*)&Bs[(wc * 64 + n * 16 + (l & 15)) * 64 + ko];
#pragma unroll
      for (int m = 0; m < 4; ++m)
#pragma unroll
        for (int n = 0; n < 4; ++n)
          acc[m][n] = __builtin_amdgcn_mfma_f32_16x16x32_bf16(aq[m], bq[n], acc[m][n], 0, 0, 0);
    }
  }
#pragma unroll
  for (int m = 0; m < 4; ++m) {
    const int row0 = bm + wr * 64 + m * 16 + (l >> 4) * 4;
#pragma unroll
    for (int n = 0; n < 4; ++n) {
      const int col = bn + wc * 64 + n * 16 + (l & 15);
      if (EPI == 0) {
        if (col < 1024) {
          const float bv = bias[col];
#pragma unroll
          for (int j = 0; j < 4; ++j)
            C1[(size_t)(row0 + j) * 1024 + col] = acc[m][n][j] + bv;
        } else {
#pragma unroll
          for (int j = 0; j < 4; ++j)
            C2[(size_t)(row0 + j) * 1024 + (col - 1024)] = __float2bfloat16(acc[m][n][j]);
        }
      } else {
        if (col < 1000) {
          const float bv = bias[col];
#pragma unroll
          for (int j = 0; j < 4; ++j)
            C1[(size_t)(row0 + j) * 1000 + col] =
                acc[m][n][j] + __bfloat162float(ADD[(size_t)(row0 + j) * 1024 + col]) + bv;
        }
      }
    }
  }
}

// ---------- recurrence (v4, FROZEN control this round) ----------
__global__ __launch_bounds__(256) void recurrence_k(
    const float* __restrict__ xw1,            // [8192][1024]
    const float* __restrict__ w2,             // [2048][2048] f32
    const __hip_bfloat16* __restrict__ w2t,   // [1024][1024] bf16, [j][k] = w2[k][j]
    __hip_bfloat16* __restrict__ hidden) {    // [8192][1024]
  __shared__ __align__(16) __hip_bfloat16 H[16 * 1024];   // 32 KiB
  __shared__ __align__(16) float accS[16 * 68];           // [r][c], pad 68
  __shared__ __align__(16) float w2blk[2][64 * 64];       // dbuf, 2 x 16 KiB
  const int tid = threadIdx.x;
  const int l = tid & 63;
  const int w = tid >> 6;
  const int R0 = blockIdx.x * 16;
  const int rT = tid >> 4;  // solve row (0..15)
  const int g  = tid & 15;  // solve col group (4 cols each)
  const int q  = l >> 4;    // frag row-quarter
  const int fr = l & 15;    // frag col within 16

  f32x4 af[16];
#pragma unroll
  for (int f = 0; f < 16; ++f) {
    const int c = (f * 4 + w) * 16 + fr;
#pragma unroll
    for (int j = 0; j < 4; ++j)
      af[f][j] = xw1[(size_t)(R0 + q * 4 + j) * 1024 + c];
  }

  auto stage = [&](int buf, int B0s) {
#pragma unroll
    for (int i = 0; i < 4; ++i) {
      const int e = i * 1024 + tid * 4;
      const int jj = e >> 6, c = e & 63;
      gload_lds16(w2 + (size_t)(B0s + jj) * 2048 + (B0s + c), &w2blk[buf][e]);
    }
  };

  stage(0, 0);
  int cur = 0;

#pragma unroll 1
  for (int b = 0; b < 16; ++b) {
    const int B0 = b * 64;
#pragma unroll
    for (int f = 0; f < 16; ++f)
      if (f == b) {
#pragma unroll
        for (int j = 0; j < 4; ++j)
          accS[(q * 4 + j) * 68 + w * 16 + fr] = af[f][j];
      }
    __syncthreads();
    if (b < 15) stage(cur ^ 1, B0 + 64);
    f32x4 ac = *(const f32x4*)&accS[rT * 68 + g * 4];
    const float* wb = w2blk[cur];
#pragma unroll
    for (int jg = 0; jg < 16; ++jg) {
      float h0 = 0.f, h1 = 0.f, h2 = 0.f, h3 = 0.f;
      if (g >= jg) {
        const int j0 = jg * 4;
        const f32x4 wr0 = *(const f32x4*)&wb[(j0 + 0) * 64 + g * 4];
        const f32x4 wr1 = *(const f32x4*)&wb[(j0 + 1) * 64 + g * 4];
        const f32x4 wr2 = *(const f32x4*)&wb[(j0 + 2) * 64 + g * 4];
        const f32x4 wr3 = *(const f32x4*)&wb[(j0 + 3) * 64 + g * 4];
        if (g == jg) {
          h0 = fmaxf(ac[0], 0.f);
          h1 = fmaxf(ac[1] + h0 * wr0[1], 0.f);
          h2 = fmaxf(ac[2] + h0 * wr0[2] + h1 * wr1[2], 0.f);
          h3 = fmaxf(ac[3] + h0 * wr0[3] + h1 * wr1[3] + h2 * wr2[3], 0.f);
        }
        const int src = (l & 48) | jg;
        const float b0 = __shfl(h0, src, 64);
        const float b1 = __shfl(h1, src, 64);
        const float b2 = __shfl(h2, src, 64);
        const float b3 = __shfl(h3, src, 64);
        if (g == jg) {
          const int k = B0 + j0;
          union { __hip_bfloat16 hh[4]; uint2 v; } u;
          u.hh[0] = __float2bfloat16(h0); u.hh[1] = __float2bfloat16(h1);
          u.hh[2] = __float2bfloat16(h2); u.hh[3] = __float2bfloat16(h3);
          *(uint2*)&H[rT * 1024 + (((k >> 3) ^ (rT & 7)) << 3) + (k & 7)] = u.v;
        } else {
#pragma unroll
          for (int i = 0; i < 4; ++i)
            ac[i] += b0 * wr0[i] + b1 * wr1[i] + b2 * wr2[i] + b3 * wr3[i];
        }
      }
    }
    __syncthreads();
    if (tid < 128) {
      const int r5 = tid >> 3, seg = tid & 7;
      const int kk = B0 + seg * 8;
      const int gsw = (kk >> 3) ^ (r5 & 7);
      const i32x4 v = *(const i32x4*)&H[r5 * 1024 + gsw * 8];
      *(i32x4*)&hidden[(size_t)(R0 + r5) * 1024 + kk] = v;
    }
    if (b < 15) {
      const int kr0 = B0 + q * 8;
      const int kr1 = B0 + 32 + q * 8;
      const bf16x8 aq0 = *(const bf16x8*)&H[fr * 1024 + (((kr0 >> 3) ^ (fr & 7)) << 3)];
      const bf16x8 aq1 = *(const bf16x8*)&H[fr * 1024 + (((kr1 >> 3) ^ (fr & 7)) << 3)];
#pragma unroll
      for (int f = 0; f < 16; ++f)
        if (f > b) {
          const int c = (f * 4 + w) * 16 + fr;
          const bf16x8 bq0 = *(const bf16x8*)&w2t[(size_t)c * 1024 + kr0];
          const bf16x8 bq1 = *(const bf16x8*)&w2t[(size_t)c * 1024 + kr1];
          af[f] = __builtin_amdgcn_mfma_f32_16x16x32_bf16(aq0, bq0, af[f], 0, 0, 0);
          af[f] = __builtin_amdgcn_mfma_f32_16x16x32_bf16(aq1, bq1, af[f], 0, 0, 0);
        }
    }
    cur ^= 1;
  }
}

extern "C" void kernel_launch(void* const* d_in, const int* in_sizes, int n_in,
                              void* d_out, int out_size, void* d_ws, size_t ws_size,
                              hipStream_t stream) {
  const float* x  = (const float*)d_in[0];
  const float* w1 = (const float*)d_in[1];
  const float* w2 = (const float*)d_in[2];
  const float* w3 = (const float*)d_in[3];
  const float* w4 = (const float*)d_in[4];
  const float* b1 = (const float*)d_in[5];
  const float* b2 = (const float*)d_in[6];
  float* out = (float*)d_out;

  char* ws = (char*)d_ws;
  size_t off = 0;
  auto alloc = [&](size_t bytes) {
    char* p = ws + off;
    off += (bytes + 255) & ~(size_t)255;
    return p;
  };
  __hip_bfloat16* x_bf = (__hip_bfloat16*)alloc(8192ull * 2048 * 2);  // hid aliases this
  float*          xw1  = (float*)alloc(8192ull * 1024 * 4);
  __hip_bfloat16* xw4  = (__hip_bfloat16*)alloc(8192ull * 1024 * 2);
  __hip_bfloat16* w14t = (__hip_bfloat16*)alloc(2048ull * 2048 * 2);
  __hip_bfloat16* w2t  = (__hip_bfloat16*)alloc(1024ull * 1024 * 2);
  __hip_bfloat16* w3t  = (__hip_bfloat16*)alloc(1024ull * 1024 * 2);
  __hip_bfloat16* hid  = x_bf;  // x_bf dead after merged GEMM

  cvt_bf16x8<<<dim3(8192), dim3(256), 0, stream>>>(x, x_bf, 8192L * 2048);

  dim3 tb(32, 8);
  // w14t rows 0-1023: w1 cols (K=2048); rows 1024-2047: w4 cols (pad >=1000 zero)
  transpose_cvt<<<dim3(64, 32), tb, 0, stream>>>(w1, w14t, 2048, 2048, 1024);
  transpose_cvt<<<dim3(64, 32), tb, 0, stream>>>(w4, w14t + 1024ull * 2048, 1000, 2048, 1000);
  transpose_cvt<<<dim3(32, 32), tb, 0, stream>>>(w2, w2t, 2048, 1024, 1024);
  transpose_cvt<<<dim3(32, 32), tb, 0, stream>>>(w3, w3t, 1000, 1024, 1000);

  // merged: [xw1 | xw4] = x @ [w1'|w4'] ; xw1 f32 (+b1), xw4 bf16
  gemm_nt<0><<<dim3(64, 16), dim3(256), 0, stream>>>(
      x_bf, w14t, 2048, b1, xw1, xw4, (const __hip_bfloat16*)nullptr);

  recurrence_k<<<dim3(512), dim3(256), 0, stream>>>(xw1, w2, w2t, hid);

  // out = hid @ w3[:1024] + xw4 + b2
  gemm_nt<1><<<dim3(64, 8), dim3(256), 0, stream>>>(
      hid, w3t, 1024, b2, out, (__hip_bfloat16*)nullptr, xw4);

  (void)in_sizes; (void)n_in; (void)out_size; (void)ws_size;
}

// Round 7
// 425.243 us; speedup vs baseline: 1.0387x; 1.0387x over previous
//
#include <hip/hip_runtime.h>
#include <hip/hip_bf16.h>

// SDNN: xw1 = x@w1[:, :1024]+b1 ; h[:,j]=relu(xw1[:,j]+h@w2[:,j]) j<1024 ;
//       out = h@w3[:1024]+x@w4+b2.
// R5->R6 (resubmit after GPU-acquisition timeout; kernel unchanged):
//   GEMMs rebuilt on the 256-tile / 512-thread / BK=64 2-phase pipeline
//   (T3-minimum recipe): double-buffered LDS (128/96 KiB), STAGE(next) issued
//   before compute, ONE raw s_barrier + vmcnt(0) per K-tile (drain hidden
//   under 64 MFMAs/wave). Recurrence + converts frozen (controls).

typedef __bf16 bf16x8 __attribute__((ext_vector_type(8)));
typedef float f32x4 __attribute__((ext_vector_type(4)));
typedef int i32x4 __attribute__((ext_vector_type(4)));

__device__ __forceinline__ void gload_lds16(const void* gsrc, void* ldst) {
#if __has_builtin(__builtin_amdgcn_global_load_lds)
  void* g = const_cast<void*>(gsrc);
  __builtin_amdgcn_global_load_lds((__attribute__((address_space(1))) void*)g,
                                   (__attribute__((address_space(3))) void*)ldst,
                                   16, 0, 0);
#else
  *(i32x4*)ldst = *(const i32x4*)gsrc;
#endif
}

// ---------- converts (frozen) ----------
__global__ __launch_bounds__(256) void cvt_bf16x8(const float* __restrict__ src,
                                                  __hip_bfloat16* __restrict__ dst,
                                                  long n) {
  long i = ((long)blockIdx.x * blockDim.x + threadIdx.x) * 8;
  if (i >= n) return;
  f32x4 a = *(const f32x4*)(src + i);
  f32x4 b = *(const f32x4*)(src + i + 4);
  union { __hip_bfloat16 h[8]; i32x4 v; } u;
#pragma unroll
  for (int j = 0; j < 4; ++j) {
    u.h[j]     = __float2bfloat16(a[j]);
    u.h[4 + j] = __float2bfloat16(b[j]);
  }
  *(i32x4*)(dst + i) = u.v;
}

__global__ __launch_bounds__(256) void transpose_cvt(const float* __restrict__ src,
                                                     __hip_bfloat16* __restrict__ dst,
                                                     int srcStride, int Kuse, int Juse) {
  __shared__ float tile[32][33];
  const int k0 = blockIdx.x * 32, j0 = blockIdx.y * 32;
  const int tx = threadIdx.x, ty = threadIdx.y;  // 32 x 8
#pragma unroll
  for (int i = 0; i < 4; ++i) {
    const int k = k0 + ty + i * 8, j = j0 + tx;
    tile[ty + i * 8][tx] = (j < Juse) ? src[(size_t)k * srcStride + j] : 0.f;
  }
  __syncthreads();
#pragma unroll
  for (int i = 0; i < 4; ++i) {
    const int j = j0 + ty + i * 8, k = k0 + tx;
    dst[(size_t)j * Kuse + k] = __float2bfloat16(tile[tx][ty + i * 8]);
  }
}

// ---------- 2-phase 256-tile GEMM ----------
// C[bm:bm+256, bn:bn+BN] = A[M][K] @ Bt[N][K]^T, 512 thr = 8 waves (2M x 4N).
// Per wave: 128 x (BN/4) output, acc[8][BN/64] f32x4.
// EPI=0 (merged x@[w1|w4]): col<1024 -> C1 f32 [.][1024] = acc+bias[col]
//                           col>=1024 -> C2 bf16 [.][1024] = bf16(acc)
// EPI=1 (out): col<1000 -> C1 f32 [.][1000] = acc + f32(ADD[row][1024]) + bias
template <int BN, int EPI>
__global__ __launch_bounds__(512, 2) void gemm2p(
    const __hip_bfloat16* __restrict__ A, const __hip_bfloat16* __restrict__ Bt, int K,
    const float* __restrict__ bias, float* __restrict__ C1,
    __hip_bfloat16* __restrict__ C2, const __hip_bfloat16* __restrict__ ADD) {
  constexpr int WN = BN / 4;        // wave N-tile (64 or 32)
  constexpr int NR = WN / 16;       // N frags per wave (4 or 2)
  constexpr int BR = BN / 64;       // B staging rounds (4 or 2)
  __shared__ __align__(16) __hip_bfloat16 As[2][256 * 64];
  __shared__ __align__(16) __hip_bfloat16 Bs[2][BN * 64];
  const int tid = threadIdx.x;
  const int l = tid & 63;
  const int w = tid >> 6;
  const int wr = w >> 2, wc = w & 3;    // 2 x 4 wave grid
  const int bm = blockIdx.x * 256;
  const int bn = blockIdx.y * BN;
  const int sr = tid >> 3;              // staging row within round (0..63)
  const int sk = (tid & 7) * 8;         // staging k-offset (elements)

  f32x4 acc[8][NR];
#pragma unroll
  for (int m = 0; m < 8; ++m)
#pragma unroll
    for (int n = 0; n < NR; ++n) acc[m][n] = f32x4{0.f, 0.f, 0.f, 0.f};

  auto STAGE = [&](int buf, int kt) {
#pragma unroll
    for (int i = 0; i < 4; ++i)
      gload_lds16(A + (size_t)(bm + i * 64 + sr) * K + kt + sk,
                  &As[buf][(i * 64 + sr) * 64 + sk]);
#pragma unroll
    for (int i = 0; i < BR; ++i)
      gload_lds16(Bt + (size_t)(bn + i * 64 + sr) * K + kt + sk,
                  &Bs[buf][(i * 64 + sr) * 64 + sk]);
  };

  const int NT = K >> 6;
  STAGE(0, 0);
  asm volatile("s_waitcnt vmcnt(0)" ::: "memory");
  __builtin_amdgcn_s_barrier();

  int cur = 0;
#pragma unroll 1
  for (int t = 0; t < NT; ++t) {
    if (t + 1 < NT) STAGE(cur ^ 1, (t + 1) * 64);   // overlapped with compute
#pragma unroll
    for (int kk = 0; kk < 64; kk += 32) {
      const int ko = kk + (l >> 4) * 8;
      bf16x8 aq[8], bq[NR];
#pragma unroll
      for (int m = 0; m < 8; ++m)
        aq[m] = *(const bf16x8*)&As[cur][(wr * 128 + m * 16 + (l & 15)) * 64 + ko];
#pragma unroll
      for (int n = 0; n < NR; ++n)
        bq[n] = *(const bf16x8*)&Bs[cur][(wc * WN + n * 16 + (l & 15)) * 64 + ko];
#pragma unroll
      for (int m = 0; m < 8; ++m)
#pragma unroll
        for (int n = 0; n < NR; ++n)
          acc[m][n] = __builtin_amdgcn_mfma_f32_16x16x32_bf16(aq[m], bq[n], acc[m][n], 0, 0, 0);
    }
    asm volatile("s_waitcnt vmcnt(0)" ::: "memory");  // next tile staged (hidden)
    __builtin_amdgcn_s_barrier();                     // + everyone done reading cur
    cur ^= 1;
  }

#pragma unroll
  for (int m = 0; m < 8; ++m) {
    const int row0 = bm + wr * 128 + m * 16 + (l >> 4) * 4;
#pragma unroll
    for (int n = 0; n < NR; ++n) {
      const int col = bn + wc * WN + n * 16 + (l & 15);
      if (EPI == 0) {
        if (col < 1024) {
          const float bv = bias[col];
#pragma unroll
          for (int j = 0; j < 4; ++j)
            C1[(size_t)(row0 + j) * 1024 + col] = acc[m][n][j] + bv;
        } else {
#pragma unroll
          for (int j = 0; j < 4; ++j)
            C2[(size_t)(row0 + j) * 1024 + (col - 1024)] = __float2bfloat16(acc[m][n][j]);
        }
      } else {
        if (col < 1000) {
          const float bv = bias[col];
#pragma unroll
          for (int j = 0; j < 4; ++j)
            C1[(size_t)(row0 + j) * 1000 + col] =
                acc[m][n][j] + __bfloat162float(ADD[(size_t)(row0 + j) * 1024 + col]) + bv;
        }
      }
    }
  }
}

// ---------- recurrence (v4, FROZEN control) ----------
__global__ __launch_bounds__(256) void recurrence_k(
    const float* __restrict__ xw1,            // [8192][1024]
    const float* __restrict__ w2,             // [2048][2048] f32
    const __hip_bfloat16* __restrict__ w2t,   // [1024][1024] bf16, [j][k] = w2[k][j]
    __hip_bfloat16* __restrict__ hidden) {    // [8192][1024]
  __shared__ __align__(16) __hip_bfloat16 H[16 * 1024];   // 32 KiB
  __shared__ __align__(16) float accS[16 * 68];           // [r][c], pad 68
  __shared__ __align__(16) float w2blk[2][64 * 64];       // dbuf, 2 x 16 KiB
  const int tid = threadIdx.x;
  const int l = tid & 63;
  const int w = tid >> 6;
  const int R0 = blockIdx.x * 16;
  const int rT = tid >> 4;  // solve row (0..15)
  const int g  = tid & 15;  // solve col group (4 cols each)
  const int q  = l >> 4;    // frag row-quarter
  const int fr = l & 15;    // frag col within 16

  f32x4 af[16];
#pragma unroll
  for (int f = 0; f < 16; ++f) {
    const int c = (f * 4 + w) * 16 + fr;
#pragma unroll
    for (int j = 0; j < 4; ++j)
      af[f][j] = xw1[(size_t)(R0 + q * 4 + j) * 1024 + c];
  }

  auto stage = [&](int buf, int B0s) {
#pragma unroll
    for (int i = 0; i < 4; ++i) {
      const int e = i * 1024 + tid * 4;
      const int jj = e >> 6, c = e & 63;
      gload_lds16(w2 + (size_t)(B0s + jj) * 2048 + (B0s + c), &w2blk[buf][e]);
    }
  };

  stage(0, 0);
  int cur = 0;

#pragma unroll 1
  for (int b = 0; b < 16; ++b) {
    const int B0 = b * 64;
#pragma unroll
    for (int f = 0; f < 16; ++f)
      if (f == b) {
#pragma unroll
        for (int j = 0; j < 4; ++j)
          accS[(q * 4 + j) * 68 + w * 16 + fr] = af[f][j];
      }
    __syncthreads();
    if (b < 15) stage(cur ^ 1, B0 + 64);
    f32x4 ac = *(const f32x4*)&accS[rT * 68 + g * 4];
    const float* wb = w2blk[cur];
#pragma unroll
    for (int jg = 0; jg < 16; ++jg) {
      float h0 = 0.f, h1 = 0.f, h2 = 0.f, h3 = 0.f;
      if (g >= jg) {
        const int j0 = jg * 4;
        const f32x4 wr0 = *(const f32x4*)&wb[(j0 + 0) * 64 + g * 4];
        const f32x4 wr1 = *(const f32x4*)&wb[(j0 + 1) * 64 + g * 4];
        const f32x4 wr2 = *(const f32x4*)&wb[(j0 + 2) * 64 + g * 4];
        const f32x4 wr3 = *(const f32x4*)&wb[(j0 + 3) * 64 + g * 4];
        if (g == jg) {
          h0 = fmaxf(ac[0], 0.f);
          h1 = fmaxf(ac[1] + h0 * wr0[1], 0.f);
          h2 = fmaxf(ac[2] + h0 * wr0[2] + h1 * wr1[2], 0.f);
          h3 = fmaxf(ac[3] + h0 * wr0[3] + h1 * wr1[3] + h2 * wr2[3], 0.f);
        }
        const int src = (l & 48) | jg;
        const float b0 = __shfl(h0, src, 64);
        const float b1 = __shfl(h1, src, 64);
        const float b2 = __shfl(h2, src, 64);
        const float b3 = __shfl(h3, src, 64);
        if (g == jg) {
          const int k = B0 + j0;
          union { __hip_bfloat16 hh[4]; uint2 v; } u;
          u.hh[0] = __float2bfloat16(h0); u.hh[1] = __float2bfloat16(h1);
          u.hh[2] = __float2bfloat16(h2); u.hh[3] = __float2bfloat16(h3);
          *(uint2*)&H[rT * 1024 + (((k >> 3) ^ (rT & 7)) << 3) + (k & 7)] = u.v;
        } else {
#pragma unroll
          for (int i = 0; i < 4; ++i)
            ac[i] += b0 * wr0[i] + b1 * wr1[i] + b2 * wr2[i] + b3 * wr3[i];
        }
      }
    }
    __syncthreads();
    if (tid < 128) {
      const int r5 = tid >> 3, seg = tid & 7;
      const int kk = B0 + seg * 8;
      const int gsw = (kk >> 3) ^ (r5 & 7);
      const i32x4 v = *(const i32x4*)&H[r5 * 1024 + gsw * 8];
      *(i32x4*)&hidden[(size_t)(R0 + r5) * 1024 + kk] = v;
    }
    if (b < 15) {
      const int kr0 = B0 + q * 8;
      const int kr1 = B0 + 32 + q * 8;
      const bf16x8 aq0 = *(const bf16x8*)&H[fr * 1024 + (((kr0 >> 3) ^ (fr & 7)) << 3)];
      const bf16x8 aq1 = *(const bf16x8*)&H[fr * 1024 + (((kr1 >> 3) ^ (fr & 7)) << 3)];
#pragma unroll
      for (int f = 0; f < 16; ++f)
        if (f > b) {
          const int c = (f * 4 + w) * 16 + fr;
          const bf16x8 bq0 = *(const bf16x8*)&w2t[(size_t)c * 1024 + kr0];
          const bf16x8 bq1 = *(const bf16x8*)&w2t[(size_t)c * 1024 + kr1];
          af[f] = __builtin_amdgcn_mfma_f32_16x16x32_bf16(aq0, bq0, af[f], 0, 0, 0);
          af[f] = __builtin_amdgcn_mfma_f32_16x16x32_bf16(aq1, bq1, af[f], 0, 0, 0);
        }
    }
    cur ^= 1;
  }
}

extern "C" void kernel_launch(void* const* d_in, const int* in_sizes, int n_in,
                              void* d_out, int out_size, void* d_ws, size_t ws_size,
                              hipStream_t stream) {
  const float* x  = (const float*)d_in[0];
  const float* w1 = (const float*)d_in[1];
  const float* w2 = (const float*)d_in[2];
  const float* w3 = (const float*)d_in[3];
  const float* w4 = (const float*)d_in[4];
  const float* b1 = (const float*)d_in[5];
  const float* b2 = (const float*)d_in[6];
  float* out = (float*)d_out;

  char* ws = (char*)d_ws;
  size_t off = 0;
  auto alloc = [&](size_t bytes) {
    char* p = ws + off;
    off += (bytes + 255) & ~(size_t)255;
    return p;
  };
  __hip_bfloat16* x_bf = (__hip_bfloat16*)alloc(8192ull * 2048 * 2);  // hid aliases this
  float*          xw1  = (float*)alloc(8192ull * 1024 * 4);
  __hip_bfloat16* xw4  = (__hip_bfloat16*)alloc(8192ull * 1024 * 2);
  __hip_bfloat16* w14t = (__hip_bfloat16*)alloc(2048ull * 2048 * 2);
  __hip_bfloat16* w2t  = (__hip_bfloat16*)alloc(1024ull * 1024 * 2);
  __hip_bfloat16* w3t  = (__hip_bfloat16*)alloc(1024ull * 1024 * 2);
  __hip_bfloat16* hid  = x_bf;  // x_bf dead after merged GEMM

  cvt_bf16x8<<<dim3(8192), dim3(256), 0, stream>>>(x, x_bf, 8192L * 2048);

  dim3 tb(32, 8);
  // w14t rows 0-1023: w1 cols (K=2048); rows 1024-2047: w4 cols (pad >=1000 zero)
  transpose_cvt<<<dim3(64, 32), tb, 0, stream>>>(w1, w14t, 2048, 2048, 1024);
  transpose_cvt<<<dim3(64, 32), tb, 0, stream>>>(w4, w14t + 1024ull * 2048, 1000, 2048, 1000);
  transpose_cvt<<<dim3(32, 32), tb, 0, stream>>>(w2, w2t, 2048, 1024, 1024);
  transpose_cvt<<<dim3(32, 32), tb, 0, stream>>>(w3, w3t, 1000, 1024, 1000);

  // merged: [xw1 | xw4] = x @ [w1'|w4'] ; xw1 f32 (+b1), xw4 bf16
  gemm2p<256, 0><<<dim3(32, 8), dim3(512), 0, stream>>>(
      x_bf, w14t, 2048, b1, xw1, xw4, (const __hip_bfloat16*)nullptr);

  recurrence_k<<<dim3(512), dim3(256), 0, stream>>>(xw1, w2, w2t, hid);

  // out = hid @ w3[:1024] + xw4 + b2
  gemm2p<128, 1><<<dim3(32, 8), dim3(512), 0, stream>>>(
      hid, w3t, 1024, b2, out, (__hip_bfloat16*)nullptr, xw4);

  (void)in_sizes; (void)n_in; (void)out_size; (void)ws_size;
}